// Round 1
// baseline (287.354 us; speedup 1.0000x reference)
//
#include <hip/hip_runtime.h>

#define CG 16      // channels per group (in and out)
#define H 320
#define W 320
#define BATCH 8
#define NGROUP 4
#define XPT 5      // x positions per thread (64 lanes * 5 = 320 = W)
#define ROWS 4     // y rows per block (256 threads / 64 lanes)

__global__ __launch_bounds__(256) void mergedconv_kernel(
    const float* __restrict__ x, const float* __restrict__ wgt,
    const float* __restrict__ bias, float* __restrict__ out) {
  __shared__ float sw[CG][3][CG][3];  // [ic][ky][oc][kx] — contiguous 48 floats per (ic,ky)
  __shared__ float sb[CG];

  const int tid = threadIdx.x;
  const int bg = blockIdx.y;           // b * NGROUP + g
  const int g = bg & (NGROUP - 1);
  const int b = bg >> 2;
  const int d = (g == 0) ? 1 : (g == 1) ? 6 : (g == 2) ? 12 : 18;

  // Stage this group's weights: global layout [oc][ic][ky][kx], group g is a
  // contiguous 16*16*9 chunk. Transpose into [ic][ky][oc][kx] in LDS.
  const float* wp = wgt + g * (CG * CG * 9);
  for (int i = tid; i < CG * CG * 9; i += 256) {
    int oc = i / (CG * 9);
    int r  = i % (CG * 9);
    int ic = r / 9;
    int t  = r % 9;
    sw[ic][t / 3][oc][t % 3] = wp[i];
  }
  if (tid < CG) sb[tid] = bias[g * CG + tid];
  __syncthreads();

  const int row  = tid >> 6;           // each wave = one output row
  const int lane = tid & 63;
  const int y    = blockIdx.x * ROWS + row;
  const int x0   = lane * XPT;

  float acc[CG][XPT];
#pragma unroll
  for (int oc = 0; oc < CG; ++oc)
#pragma unroll
    for (int j = 0; j < XPT; ++j) acc[oc][j] = 0.f;

  const float* xg = x + (size_t)(b * (NGROUP * CG) + g * CG) * H * W;

#pragma unroll 1
  for (int ic = 0; ic < CG; ++ic) {
    const float* xc = xg + (size_t)ic * H * W;
#pragma unroll 1
    for (int ky = 0; ky < 3; ++ky) {
      const int yy = y + (ky - 1) * d;
      if (yy < 0 || yy >= H) continue;   // wave-uniform branch (zero padding)
      const float* xr = xc + (size_t)yy * W;
      float in0[XPT], in1[XPT], in2[XPT];
      const int xm = x0 - d, xp = x0 + d;
#pragma unroll
      for (int j = 0; j < XPT; ++j) in0[j] = (xm + j >= 0) ? xr[xm + j] : 0.f;
#pragma unroll
      for (int j = 0; j < XPT; ++j) in1[j] = xr[x0 + j];     // always in-bounds
#pragma unroll
      for (int j = 0; j < XPT; ++j) in2[j] = (xp + j < W) ? xr[xp + j] : 0.f;
#pragma unroll
      for (int oc = 0; oc < CG; ++oc) {
        const float w0 = sw[ic][ky][oc][0];
        const float w1 = sw[ic][ky][oc][1];
        const float w2 = sw[ic][ky][oc][2];
#pragma unroll
        for (int j = 0; j < XPT; ++j)
          acc[oc][j] = fmaf(in0[j], w0, fmaf(in1[j], w1, fmaf(in2[j], w2, acc[oc][j])));
      }
    }
  }

#pragma unroll
  for (int oc = 0; oc < CG; ++oc) {
    float* orow = out + ((size_t)(b * (NGROUP * CG) + g * CG + oc) * H + y) * W + x0;
    const float bv = sb[oc];
#pragma unroll
    for (int j = 0; j < XPT; ++j) orow[j] = acc[oc][j] + bv;
  }
}

extern "C" void kernel_launch(void* const* d_in, const int* in_sizes, int n_in,
                              void* d_out, int out_size, void* d_ws, size_t ws_size,
                              hipStream_t stream) {
  const float* x    = (const float*)d_in[0];
  const float* wgt  = (const float*)d_in[1];
  const float* bias = (const float*)d_in[2];
  float* out        = (float*)d_out;

  dim3 grid(H / ROWS, BATCH * NGROUP);
  mergedconv_kernel<<<grid, dim3(256), 0, stream>>>(x, wgt, bias, out);
}

// Round 2
// 283.465 us; speedup vs baseline: 1.0137x; 1.0137x over previous
//
#include <hip/hip_runtime.h>

typedef short short8 __attribute__((ext_vector_type(8)));
typedef float floatx4 __attribute__((ext_vector_type(4)));

#define H 320
#define W 320
#define CG 16      // channels per group
#define CGP 24     // padded ic stride in LDS (48 B: 16B-aligned, bank-conflict-free)
#define NCH 64
#define HALFW 160  // cols per block

__device__ __forceinline__ unsigned short f2bf(float f) {
  unsigned u = __float_as_uint(f);
  return (unsigned short)((u + 0x7FFFu + ((u >> 16) & 1u)) >> 16);  // RNE
}

// Block: 256 thr = 4 waves. Covers (b, g, half-row, output rows {y0, y0+d, y0+2d, y0+3d}).
// The 6 staged input rows R[j] = (4q+j-1)*d + r are shared: wave w, tap-row ky uses R[w+ky].
template<int G>
__global__ __launch_bounds__(256, 2) void conv_mfma(
    const float* __restrict__ x, const float* __restrict__ wgt,
    const float* __restrict__ bias, float* __restrict__ out) {
  constexpr int DIL = (G == 0) ? 1 : (G == 1) ? 6 : (G == 2) ? 12 : 18;
  constexpr int WH = HALFW + 2 * DIL;        // staged cols (with halo)
  constexpr int NPASS = (WH + 63) / 64;
  __shared__ unsigned short lds[6][WH][CGP]; // [row][col][ic] bf16

  const int tid = threadIdx.x;
  const int q = blockIdx.x / DIL;
  const int r = blockIdx.x - q * DIL;
  const int wbase = blockIdx.y * HALFW;
  const int b = blockIdx.z;

  // ---- stage 6 input rows: fp32 -> bf16, transpose to [col][ic] ----
  const int icp = tid & 7;   // handles ics {2icp, 2icp+1}
  const int cp = tid >> 3;   // 0..31; cols {64p+cp, 64p+cp+32} -> 2 lanes/bank writes
  const float* xg = x + (size_t)(b * NCH + G * CG) * (H * W);
  const float* r0base = xg + (size_t)(2 * icp) * (H * W);
#pragma unroll 1
  for (int j = 0; j < 6; ++j) {
    const int yy = (4 * q + j - 1) * DIL + r;
    const bool rv = (yy >= 0) & (yy < H);
    const int yyc = yy < 0 ? 0 : (yy >= H ? H - 1 : yy);
    const float* row0 = r0base + (size_t)yyc * W;
    const float* row1 = row0 + (size_t)(H * W);
#pragma unroll
    for (int p = 0; p < NPASS; ++p) {
#pragma unroll
      for (int hh = 0; hh < 2; ++hh) {
        const int cc = p * 64 + cp + hh * 32;
        if (cc < WH) {
          const int gc = wbase + cc - DIL;
          const bool ok = rv & (gc >= 0) & (gc < W);
          const int gcc = gc < 0 ? 0 : (gc >= W ? W - 1 : gc);
          float f0 = row0[gcc];
          float f1 = row1[gcc];
          if (!ok) { f0 = 0.f; f1 = 0.f; }
          const unsigned pk = (unsigned)f2bf(f0) | ((unsigned)f2bf(f1) << 16);
          *(unsigned*)&lds[j][cc][2 * icp] = pk;
        }
      }
    }
  }

  // ---- A-fragments (weights) in registers; K=32 = 2 taps x 16 ic ----
  // k-octet of lane-group z: tap = 2t + (z>>1), ic = (z&1)*8 + j  (same map on B)
  const int lane = tid & 63;
  const int w = tid >> 6;
  const int ocA = lane & 15;
  const int z = lane >> 4;
  const int icq = z & 1;
  short8 aw[5];
  const float* wp = wgt + (size_t)(G * CG + ocA) * (CG * 9);
#pragma unroll
  for (int t = 0; t < 5; ++t) {
    const int tp = 2 * t + (z >> 1);
    const int ky = tp < 9 ? tp / 3 : 0;
    const int kx = tp < 9 ? tp - (tp / 3) * 3 : 0;
#pragma unroll
    for (int jj = 0; jj < 8; ++jj) {
      const int ic = icq * 8 + jj;
      const float v = (tp < 9) ? wp[ic * 9 + ky * 3 + kx] : 0.f;
      aw[t][jj] = (short)f2bf(v);
    }
  }
  float bv[4];
#pragma unroll
  for (int rg = 0; rg < 4; ++rg) bv[rg] = bias[G * CG + z * 4 + rg];

  __syncthreads();

  // ---- compute: wave w owns output row y = (4q+w)*d + r ----
  const int y = (4 * q + w) * DIL + r;
  if (y < H) {
    const int pxl = lane & 15;
    float* outb = out + (size_t)(b * NCH + G * CG) * (H * W) + (size_t)y * W + wbase;
#pragma unroll 1
    for (int tile = 0; tile < HALFW / 16; ++tile) {
      floatx4 acc = {0.f, 0.f, 0.f, 0.f};
#pragma unroll
      for (int t = 0; t < 5; ++t) {
        const int tp = 2 * t + (z >> 1);
        const int ky = tp < 9 ? tp / 3 : 0;
        const int kx = tp < 9 ? tp - (tp / 3) * 3 : 0;
        const int cc = tile * 16 + pxl + kx * DIL;  // lds col = global col - wbase + d
        const short8 bf = *(const short8*)&lds[w + ky][cc][icq * 8];
        acc = __builtin_amdgcn_mfma_f32_16x16x32_bf16(aw[t], bf, acc, 0, 0, 0);
      }
      const int pxg = tile * 16 + pxl;
#pragma unroll
      for (int rg = 0; rg < 4; ++rg) {
        // C/D: col = lane&15 (px), row = 4z+rg (oc)  [m89-verified layout]
        outb[(size_t)(z * 4 + rg) * (H * W) + pxg] = acc[rg] + bv[rg];
      }
    }
  }
}

extern "C" void kernel_launch(void* const* d_in, const int* in_sizes, int n_in,
                              void* d_out, int out_size, void* d_ws, size_t ws_size,
                              hipStream_t stream) {
  const float* x    = (const float*)d_in[0];
  const float* wgt  = (const float*)d_in[1];
  const float* bias = (const float*)d_in[2];
  float* out        = (float*)d_out;

  const dim3 blk(256);
  // rows covered: (4q+w)*d + r ; nblk_y = d * ceil(ceil(320/d)/4)
  conv_mfma<0><<<dim3(80, 2, 8), blk, 0, stream>>>(x, wgt, bias, out);
  conv_mfma<1><<<dim3(84, 2, 8), blk, 0, stream>>>(x, wgt, bias, out);
  conv_mfma<2><<<dim3(84, 2, 8), blk, 0, stream>>>(x, wgt, bias, out);
  conv_mfma<3><<<dim3(90, 2, 8), blk, 0, stream>>>(x, wgt, bias, out);
}

// Round 3
// 156.910 us; speedup vs baseline: 1.8313x; 1.8065x over previous
//
#include <hip/hip_runtime.h>

typedef short short8 __attribute__((ext_vector_type(8)));
typedef short short4_t __attribute__((ext_vector_type(4)));
typedef float floatx4 __attribute__((ext_vector_type(4)));
typedef unsigned short ushort_t;
typedef unsigned int uint32;

#define H 320
#define W 320
#define CG 16
#define NCH 64
#define CGP 20       // ushort stride per LDS col (40B): conflict-free b64 frag reads
#define HALFW 160

__device__ __forceinline__ ushort_t f2bf(float f) {
  unsigned u = __float_as_uint(f);
  return (ushort_t)((u + 0x7FFFu + ((u >> 16) & 1u)) >> 16);  // RNE
}

// Block: 256 thr = 4 waves; covers (b, g, half-row, output rows {y0, y0+d, y0+2d, y0+3d}).
// 6 staged input rows shared by the 4 waves (1.5x row amplification).
template<int G>
__device__ __forceinline__ void conv_group(
    const float* __restrict__ x, const float* __restrict__ wgt,
    const float* __restrict__ bias, float* __restrict__ out, ushort_t* lds) {
  constexpr int DIL   = (G == 0) ? 1 : (G == 1) ? 6 : (G == 2) ? 12 : 18;
  constexpr int KOFF  = DIL & 1;                 // keep even global col <-> even lds col
  constexpr int SHIFT = DIL + KOFF;              // lds col c <-> global col wbase + c - SHIFT
  constexpr int WH    = (HALFW + 2 * DIL + KOFF + 1) & ~1;  // staged cols (even)
  constexpr int NPASS = (WH + 63) / 64;
  constexpr int BX    = ((H + 4 * DIL - 1) / (4 * DIL)) * DIL;  // 80/84/84/90

  const int bx = blockIdx.x;
  if (bx >= BX) return;
  const int tid   = threadIdx.x;
  const int q     = bx / DIL;
  const int r     = bx % DIL;
  const int wbase = blockIdx.y * HALFW;
  const int b     = blockIdx.z >> 2;

  ushort_t* tile = lds;                    // [6][WH][CGP]
  ushort_t* swt  = lds + 6 * WH * CGP;     // [5][4][16][8] A-fragment table

  // ---- build weight A-fragment table in LDS (bf16) ----
  // lane (oc=lane&15, z=lane>>4), frag t, elem jj <-> tap 2t+(z>>1), ic (z&1)*8+jj
  uint32* swt32 = (uint32*)swt;
#pragma unroll
  for (int k = 0; k < 5; ++k) {
    const int s = tid + k * 256;           // 1280 u32 entries
    const int jp = s & 3, oc = (s >> 2) & 15, z = (s >> 6) & 3, t = s >> 8;
    const int tp = 2 * t + (z >> 1);
    uint32 pk = 0;
    if (tp < 9) {
      const float* wp = wgt + ((size_t)(G * CG + oc) * CG + (z & 1) * 8 + 2 * jp) * 9 + tp;
      pk = (uint32)f2bf(wp[0]) | ((uint32)f2bf(wp[9]) << 16);
    }
    swt32[s] = pk;
  }

  // ---- stage 6 input rows: float2 loads, pack 2 channels -> [col][ic] bf16 ----
  const int cpair = tid & 31;              // cols {2cpair, 2cpair+1} per 64-col pass
  const int icp   = tid >> 5;              // channels {2icp, 2icp+1}
  const float* xc0 = x + (size_t)(b * NCH + G * CG + 2 * icp) * (H * W);
  const float* xc1 = xc0 + H * W;
  uint32* tile32 = (uint32*)tile;
#pragma unroll 1
  for (int j = 0; j < 6; ++j) {
    const int yy = (4 * q + j - 1) * DIL + r;
    const bool rv = (yy >= 0) && (yy < H);
    const int yyc = yy < 0 ? 0 : (yy >= H ? H - 1 : yy);
    const float* r0 = xc0 + (size_t)yyc * W;
    const float* r1 = xc1 + (size_t)yyc * W;
#pragma unroll
    for (int p = 0; p < NPASS; ++p) {
      const int c0 = p * 64 + 2 * cpair;
      if (c0 < WH) {
        const int gc = wbase + c0 - SHIFT;  // even -> 8B-aligned float2
        float a0, a1, b0v, b1v;
        if (rv && gc >= 0 && gc + 1 < W) {
          const float2 va = *(const float2*)(r0 + gc);
          const float2 vb = *(const float2*)(r1 + gc);
          a0 = va.x; a1 = va.y; b0v = vb.x; b1v = vb.y;
        } else {
          const bool k0 = rv && gc >= 0 && gc < W;
          const bool k1 = rv && gc + 1 >= 0 && gc + 1 < W;
          a0  = k0 ? r0[gc] : 0.f;
          a1  = k1 ? r0[gc + 1] : 0.f;
          b0v = k0 ? r1[gc] : 0.f;
          b1v = k1 ? r1[gc + 1] : 0.f;
        }
        tile32[(j * WH + c0) * (CGP / 2) + icp]     = (uint32)f2bf(a0) | ((uint32)f2bf(b0v) << 16);
        tile32[(j * WH + c0 + 1) * (CGP / 2) + icp] = (uint32)f2bf(a1) | ((uint32)f2bf(b1v) << 16);
      }
    }
  }

  __syncthreads();

  // ---- compute: wave wv owns output row y = (4q+wv)*d + r ----
  const int lane = tid & 63;
  const int wv   = tid >> 6;
  const int y    = (4 * q + wv) * DIL + r;
  if (y >= H) return;                      // no barriers after this point

  const int ocA = lane & 15;
  const int z   = lane >> 4;
  const int icq = z & 1;
  const int pxl = lane & 15;

  short8 aw[5];
#pragma unroll
  for (int t = 0; t < 5; ++t)
    aw[t] = *(const short8*)&swt[((t * 4 + z) * 16 + ocA) * 8];

  float bv[4];
#pragma unroll
  for (int rg = 0; rg < 4; ++rg) bv[rg] = bias[G * CG + z * 4 + rg];

  float* outb = out + (size_t)(b * NCH + G * CG) * (H * W) + (size_t)y * W + wbase;

#pragma unroll 2
  for (int ti = 0; ti < HALFW / 16; ++ti) {
    floatx4 acc = {0.f, 0.f, 0.f, 0.f};
#pragma unroll
    for (int t = 0; t < 5; ++t) {
      const int tp = 2 * t + (z >> 1);
      const int ky = tp < 9 ? tp / 3 : 0;
      const int kx = tp < 9 ? tp % 3 : 0;
      const int cc = ti * 16 + pxl + kx * DIL + KOFF;
      const ushort_t* pf = &tile[((wv + ky) * WH + cc) * CGP + icq * 8];
      const short4_t lo = *(const short4_t*)pf;       // 8B-aligned, conflict-free
      const short4_t hi = *(const short4_t*)(pf + 4);
      const short8 bf = {lo[0], lo[1], lo[2], lo[3], hi[0], hi[1], hi[2], hi[3]};
      acc = __builtin_amdgcn_mfma_f32_16x16x32_bf16(aw[t], bf, acc, 0, 0, 0);
    }
    const int pxg = ti * 16 + pxl;
#pragma unroll
    for (int rg = 0; rg < 4; ++rg)
      outb[(size_t)(z * 4 + rg) * (H * W) + pxg] = acc[rg] + bv[rg];  // C/D: col=lane&15, row=4z+rg
  }
}

extern "C" __global__ void __launch_bounds__(256, 3) conv_all(
    const float* __restrict__ x, const float* __restrict__ wgt,
    const float* __restrict__ bias, float* __restrict__ out) {
  extern __shared__ ushort_t lds[];
  switch (blockIdx.z & 3) {
    case 0: conv_group<0>(x, wgt, bias, out, lds); break;
    case 1: conv_group<1>(x, wgt, bias, out, lds); break;
    case 2: conv_group<2>(x, wgt, bias, out, lds); break;
    default: conv_group<3>(x, wgt, bias, out, lds); break;
  }
}

extern "C" void kernel_launch(void* const* d_in, const int* in_sizes, int n_in,
                              void* d_out, int out_size, void* d_ws, size_t ws_size,
                              hipStream_t stream) {
  const float* x    = (const float*)d_in[0];
  const float* wgt  = (const float*)d_in[1];
  const float* bias = (const float*)d_in[2];
  float* out        = (float*)d_out;

  // dynamic LDS = max over groups: G3 tile 6*196*20 + 2560 table = 26080 ushorts
  const size_t lds_bytes = (size_t)(6 * 196 * 20 + 5 * 4 * 16 * 8) * 2;  // 52160
  conv_all<<<dim3(90, 2, 32), dim3(256), lds_bytes, stream>>>(x, wgt, bias, out);
}

// Round 4
// 120.834 us; speedup vs baseline: 2.3781x; 1.2986x over previous
//
#include <hip/hip_runtime.h>

typedef short short8 __attribute__((ext_vector_type(8)));
typedef short short4_t __attribute__((ext_vector_type(4)));
typedef float floatx4 __attribute__((ext_vector_type(4)));
typedef unsigned short ushort_t;
typedef unsigned int uint32;

#define H 320
#define W 320
#define CG 16
#define NCH 64
#define CGP 20       // ushort stride per LDS col (40B): conflict-free b64 frag reads
#define HALFW 160
#define NBLK 192     // blocks per group: 4*192 = 768 = 256 CU * 3 resident

__device__ __forceinline__ ushort_t f2bf(float f) {
  unsigned u = __float_as_uint(f);
  return (ushort_t)((u + 0x7FFFu + ((u >> 16) & 1u)) >> 16);  // RNE
}

// Persistent-ish block: loops over row-quad tasks with T14 pipeline:
// [issue loads(next) -> regs] [compute(cur) from LDS] [barrier] [cvt+write(next)] [barrier]
template<int G>
__device__ __forceinline__ void conv_group(
    const float* __restrict__ x, const float* __restrict__ wgt,
    const float* __restrict__ bias, float* __restrict__ out, ushort_t* lds) {
  constexpr int DIL   = (G == 0) ? 1 : (G == 1) ? 6 : (G == 2) ? 12 : 18;
  constexpr int KOFF  = DIL & 1;                    // even global col <-> even lds col
  constexpr int SHIFT = DIL + KOFF;                 // lds col c <-> global col wb + c - SHIFT
  constexpr int WH    = (HALFW + 2 * DIL + KOFF + 1) & ~1;
  constexpr int NP    = (WH + 63) / 64;
  constexpr int BX    = ((H + 4 * DIL - 1) / (4 * DIL)) * DIL;  // 80/84/84/90
  constexpr int NT    = BX * 2 * 8;                 // tasks for this group

  const int tid = threadIdx.x;
  ushort_t* tile = lds;                             // [6][WH][CGP] bf16
  uint32* tile32 = (uint32*)lds;
  ushort_t* swt = lds + 6 * WH * CGP;               // [5][4][16][8] A-frag table
  uint32* swt32 = (uint32*)swt;

  // ---- weight A-fragment table (once per block) ----
#pragma unroll
  for (int k = 0; k < 5; ++k) {
    const int s = tid + k * 256;
    const int jp = s & 3, oc = (s >> 2) & 15, zz = (s >> 6) & 3, t = s >> 8;
    const int tp = 2 * t + (zz >> 1);
    uint32 pk = 0;
    if (tp < 9) {
      const float* wp = wgt + ((size_t)(G * CG + oc) * CG + (zz & 1) * 8 + 2 * jp) * 9 + tp;
      pk = (uint32)f2bf(wp[0]) | ((uint32)f2bf(wp[9]) << 16);
    }
    swt32[s] = pk;
  }
  __syncthreads();

  const int lane = tid & 63;
  const int wv   = tid >> 6;
  const int ocA  = lane & 15, z = lane >> 4, icq = z & 1, pxl = lane & 15;
  short8 aw[5];
#pragma unroll
  for (int t = 0; t < 5; ++t) aw[t] = *(const short8*)&swt[((t * 4 + z) * 16 + ocA) * 8];
  float bv[4];
#pragma unroll
  for (int rg = 0; rg < 4; ++rg) bv[rg] = bias[G * CG + z * 4 + rg];

  const int cpair = tid & 31;   // cols {p*64+2c, +1}
  const int icp   = tid >> 5;   // channels {2icp, 2icp+1}

  float2 pa[6][NP], pb[6][NP];  // in-flight payload (statically indexed)

  auto DECODE = [&](int tau, int& q, int& r, int& wb, int& b) {
    const int bx = tau % BX;
    const int hb = tau / BX;    // 0..15
    b  = hb >> 1;
    wb = (hb & 1) * HALFW;
    q  = bx / DIL;
    r  = bx % DIL;
  };

  // branchless issue: clamped addresses, masking deferred to WRITE
  auto ISSUE = [&](int tau) {
    int q, r, wb, b; DECODE(tau, q, r, wb, b);
    const float* ch0 = x + ((size_t)(b * NCH + G * CG + 2 * icp)) * (H * W);
#pragma unroll
    for (int j = 0; j < 6; ++j) {
      const int yy  = (4 * q + j - 1) * DIL + r;
      const int yyc = yy < 0 ? 0 : (yy >= H ? H - 1 : yy);
      const float* r0 = ch0 + (size_t)yyc * W;
#pragma unroll
      for (int p = 0; p < NP; ++p) {
        const int gc  = wb + p * 64 + 2 * cpair - SHIFT;      // even -> 8B aligned
        const int gcc = gc < 0 ? 0 : (gc > W - 2 ? W - 2 : gc);
        pa[j][p] = *(const float2*)(r0 + gcc);
        pb[j][p] = *(const float2*)(r0 + (size_t)(H * W) + gcc);
      }
    }
  };

  auto WRITE = [&](int tau) {
    int q, r, wb, b; DECODE(tau, q, r, wb, b);
#pragma unroll
    for (int j = 0; j < 6; ++j) {
      const int yy = (4 * q + j - 1) * DIL + r;
      const bool rv = (yy >= 0) && (yy < H);
#pragma unroll
      for (int p = 0; p < NP; ++p) {
        const int c0 = p * 64 + 2 * cpair;
        const int gc = wb + c0 - SHIFT;
        const bool m = rv && (gc >= 0) && (gc < W);   // gc even, W even -> covers both cols
        const uint32 pk0 = m ? ((uint32)f2bf(pa[j][p].x) | ((uint32)f2bf(pb[j][p].x) << 16)) : 0u;
        const uint32 pk1 = m ? ((uint32)f2bf(pa[j][p].y) | ((uint32)f2bf(pb[j][p].y) << 16)) : 0u;
        if (c0 < WH) {
          tile32[(j * WH + c0) * (CGP / 2) + icp]     = pk0;
          tile32[(j * WH + c0 + 1) * (CGP / 2) + icp] = pk1;
        }
      }
    }
  };

  auto COMPUTE = [&](int tau) {
    int q, r, wb, b; DECODE(tau, q, r, wb, b);
    const int y = (4 * q + wv) * DIL + r;
    if (y >= H) return;
    float* outb = out + (size_t)(b * NCH + G * CG) * (H * W) + (size_t)y * W + wb;
#pragma unroll 2
    for (int ti = 0; ti < HALFW / 16; ++ti) {
      floatx4 acc = {0.f, 0.f, 0.f, 0.f};
#pragma unroll
      for (int t = 0; t < 5; ++t) {
        const int tp = 2 * t + (z >> 1);
        const int ky = tp < 9 ? tp / 3 : 0;
        const int kx = tp < 9 ? tp % 3 : 0;
        const int cc = ti * 16 + pxl + kx * DIL + KOFF;
        const ushort_t* pf = &tile[((wv + ky) * WH + cc) * CGP + icq * 8];
        const short4_t lo = *(const short4_t*)pf;
        const short4_t hi = *(const short4_t*)(pf + 4);
        const short8 bf = {lo[0], lo[1], lo[2], lo[3], hi[0], hi[1], hi[2], hi[3]};
        acc = __builtin_amdgcn_mfma_f32_16x16x32_bf16(aw[t], bf, acc, 0, 0, 0);
      }
      const int pxg = ti * 16 + pxl;
#pragma unroll
      for (int rg = 0; rg < 4; ++rg)
        outb[(size_t)(z * 4 + rg) * (H * W) + pxg] = acc[rg] + bv[rg];  // C/D: col=lane&15, row=4z+rg
    }
  };

  // ---- pipelined task loop ----
  int tau = blockIdx.x;
  ISSUE(tau);
  WRITE(tau);
  __syncthreads();
  while (true) {
    const int nxt = tau + NBLK;
    const bool more = (nxt < NT);          // block-uniform
    if (more) ISSUE(nxt);                  // loads in flight under compute
    COMPUTE(tau);
    if (!more) break;
    __syncthreads();                       // all reads of tile done
    WRITE(nxt);                            // vmcnt drain + cvt + ds_write
    __syncthreads();                       // tile ready
    tau = nxt;
  }
}

extern "C" __global__ void __launch_bounds__(256, 3) conv_all(
    const float* __restrict__ x, const float* __restrict__ wgt,
    const float* __restrict__ bias, float* __restrict__ out) {
  extern __shared__ ushort_t lds[];
  switch (blockIdx.z) {
    case 0: conv_group<0>(x, wgt, bias, out, lds); break;
    case 1: conv_group<1>(x, wgt, bias, out, lds); break;
    case 2: conv_group<2>(x, wgt, bias, out, lds); break;
    default: conv_group<3>(x, wgt, bias, out, lds); break;
  }
}

extern "C" void kernel_launch(void* const* d_in, const int* in_sizes, int n_in,
                              void* d_out, int out_size, void* d_ws, size_t ws_size,
                              hipStream_t stream) {
  const float* x    = (const float*)d_in[0];
  const float* wgt  = (const float*)d_in[1];
  const float* bias = (const float*)d_in[2];
  float* out        = (float*)d_out;

  // dynamic LDS = max over groups (G3): 6*196*20 + 5*4*16*8 = 26080 ushorts = 52160 B
  const size_t lds_bytes = (size_t)(6 * 196 * 20 + 5 * 4 * 16 * 8) * 2;
  conv_all<<<dim3(NBLK, 1, 4), dim3(256), lds_bytes, stream>>>(x, wgt, bias, out);
}

// Round 6
// 113.325 us; speedup vs baseline: 2.5357x; 1.0663x over previous
//
#include <hip/hip_runtime.h>
#include <hip/hip_bf16.h>

typedef short short8 __attribute__((ext_vector_type(8)));
typedef short short4_t __attribute__((ext_vector_type(4)));
typedef float floatx4 __attribute__((ext_vector_type(4)));
typedef unsigned short ushort_t;
typedef unsigned int uint32;

#define H 320
#define W 320
#define CG 16
#define NCH 64
#define CGP 20       // ushorts per LDS col (40B): conflict-free b64 frag reads
#define HALFW 160

__device__ __forceinline__ ushort_t f2bf(float f) {
  unsigned u = __float_as_uint(f);
  return (ushort_t)((u + 0x7FFFu + ((u >> 16) & 1u)) >> 16);  // RNE (weights only)
}

// LDS-only barrier: does NOT drain vmcnt -> global loads/stores stay in flight
// across it (AITER pattern). Correctness needs only LDS ordering here.
__device__ __forceinline__ void barrier_lgkm() {
  asm volatile("s_waitcnt lgkmcnt(0)" ::: "memory");
  __builtin_amdgcn_s_barrier();
}

// Block: 256 thr = 4 waves. Walks q upward within one (r, wb, b) column strip;
// ring-6 LDS row buffer: steady-state stages only 4 new rows per 4 output rows.
template<int G>
__device__ __forceinline__ void conv_group(
    const float* __restrict__ x, const float* __restrict__ wgt,
    const float* __restrict__ bias, float* __restrict__ out,
    ushort_t* lds, int bx) {
  constexpr int DIL   = (G == 0) ? 1 : (G == 1) ? 6 : (G == 2) ? 12 : 18;
  constexpr int KOFF  = DIL & 1;                 // even global col <-> even lds col
  constexpr int SHIFT = DIL + KOFF;              // lds col c <-> global col wb + c - SHIFT
  constexpr int WH    = (HALFW + 2 * DIL + KOFF + 1) & ~1;  // 164/172/184/196
  constexpr int NP    = (WH + 63) / 64;          // 3/3/3/4
  constexpr int WKS   = 16 * DIL;                // walks = DIL * 2(wb) * 8(b)
  constexpr int RPW   = (H + DIL - 1) / DIL;
  constexpr int Q     = (RPW + 3) / 4;           // 80/14/7/5 tasks per walk
  constexpr int CPW   = (G == 0) ? 12 : (G == 1) ? 2 : 1;
  constexpr int L     = (Q + CPW - 1) / CPW;     // 7/7/7/5 tasks per chunk

  const int tid = threadIdx.x;
  ushort_t* tile = lds;                          // [6][WH][CGP]
  ushort_t* swt  = lds + 6 * WH * CGP;           // [5][4][16][8] A-frag table
  uint32* swt32  = (uint32*)swt;

  // ---- weight A-fragment table (once per block) ----
#pragma unroll
  for (int k = 0; k < 5; ++k) {
    const int s = tid + k * 256;
    const int jp = s & 3, oc = (s >> 2) & 15, zz = (s >> 6) & 3, t = s >> 8;
    const int tp = 2 * t + (zz >> 1);
    uint32 pk = 0;
    if (tp < 9) {
      const float* wp = wgt + ((size_t)(G * CG + oc) * CG + (zz & 1) * 8 + 2 * jp) * 9 + tp;
      pk = (uint32)f2bf(wp[0]) | ((uint32)f2bf(wp[9]) << 16);
    }
    swt32[s] = pk;
  }
  __syncthreads();

  const int lane = tid & 63;
  const int wv   = tid >> 6;
  const int z = lane >> 4, icq = z & 1, pxl = lane & 15;
  short8 aw[5];
#pragma unroll
  for (int t = 0; t < 5; ++t) aw[t] = *(const short8*)&swt[((t * 4 + z) * 16 + (lane & 15)) * 8];
  float bv[4];
#pragma unroll
  for (int rg = 0; rg < 4; ++rg) bv[rg] = bias[G * CG + z * 4 + rg];

  // ---- decode block -> (walk, chunk) ----
  const int walk  = bx % WKS;
  const int chunk = bx / WKS;
  const int r  = walk % DIL;
  const int wb = ((walk / DIL) & 1) * HALFW;
  const int b  = walk / (2 * DIL);
  const int q0 = chunk * L;
  const int qend = (q0 + L < Q) ? q0 + L : Q;

  // ---- staging constants: thread = (col = lane, ch-quad = wv) ----
  bool zm[NP]; bool inb[NP]; int gofs[NP];
#pragma unroll
  for (int p = 0; p < NP; ++p) {
    const int c = 64 * p + lane;
    inb[p] = (c < WH);
    const int gc = wb + c - SHIFT;
    zm[p] = inb[p] & (gc >= 0) & (gc < W);
    gofs[p] = gc < 0 ? 0 : (gc >= W ? W - 1 : gc);
  }
  const float* chb = x + (size_t)(b * NCH + G * CG + 4 * wv) * (H * W);

  auto LOADR = [&](int rho, float (&rg)[NP][4]) {
    const int yy = rho * DIL + r;
    const int yyc = yy < 0 ? 0 : (yy >= H ? H - 1 : yy);
    const float* rp = chb + (size_t)yyc * W;
#pragma unroll
    for (int p = 0; p < NP; ++p)
#pragma unroll
      for (int k = 0; k < 4; ++k)
        rg[p][k] = rp[(size_t)k * (H * W) + gofs[p]];   // 256B coalesced per inst
  };

  auto CVTR = [&](int rho, int slot, float (&rg)[NP][4]) {
    const int yy = rho * DIL + r;
    const bool rv = (yy >= 0) & (yy < H);
#pragma unroll
    for (int p = 0; p < NP; ++p) {
      const bool m = rv & zm[p];
      const __hip_bfloat162 h01 = __float22bfloat162_rn(make_float2(rg[p][0], rg[p][1]));
      const __hip_bfloat162 h23 = __float22bfloat162_rn(make_float2(rg[p][2], rg[p][3]));
      uint2 pk;
      pk.x = m ? *(const uint32*)&h01 : 0u;
      pk.y = m ? *(const uint32*)&h23 : 0u;
      if (inb[p]) {
        const int c = 64 * p + lane;
        *(uint2*)&tile[(size_t)(slot * WH + c) * CGP + wv * 4] = pk;  // ds_write_b64
      }
    }
  };

  auto COMPUTE = [&](int q, int m6) {
    const int y = (4 * q + wv) * DIL + r;
    if (y >= H) return;
    const int zh = z >> 1;
    float* outb = out + (size_t)(b * NCH + G * CG) * (H * W) + (size_t)y * W + wb;
    const ushort_t* rowp[5];                 // statically indexed (unrolled t)
#pragma unroll
    for (int t = 0; t < 5; ++t) {
      const int tp = 2 * t + zh;
      const int ky = tp < 9 ? tp / 3 : 0;
      const int kx = tp < 9 ? tp - ky * 3 : 0;
      int s = m6 + wv + ky; s -= (s >= 6) ? 6 : 0;   // slot of row j = wv+ky
      rowp[t] = tile + (size_t)s * (WH * CGP) + (size_t)(pxl + kx * DIL + KOFF) * CGP + icq * 8;
    }
#pragma unroll 2
    for (int ti = 0; ti < HALFW / 16; ++ti) {
      floatx4 acc = {0.f, 0.f, 0.f, 0.f};
#pragma unroll
      for (int t = 0; t < 5; ++t) {
        const ushort_t* pf = rowp[t] + ti * 16 * CGP;
        const short4_t lo = *(const short4_t*)pf;
        const short4_t hi = *(const short4_t*)(pf + 4);
        const short8 bf = {lo[0], lo[1], lo[2], lo[3], hi[0], hi[1], hi[2], hi[3]};
        acc = __builtin_amdgcn_mfma_f32_16x16x32_bf16(aw[t], bf, acc, 0, 0, 0);
      }
      const int pxg = ti * 16 + pxl;
#pragma unroll
      for (int rg = 0; rg < 4; ++rg)
        outb[(size_t)(z * 4 + rg) * (H * W) + pxg] = acc[rg] + bv[rg];  // C/D: col=lane&15, row=4z+rg
    }
  };

  auto wrap6 = [](int v) { return v >= 6 ? v - 6 : v; };
  int m6 = (4 * q0 + 5) % 6;                 // slot of row rho = 4q-1 (ring-6)

  // ---- prologue: stage 6 rows (pairwise pipelined) ----
  {
    float ra[NP][4], rb[NP][4];
    LOADR(4 * q0 - 1, ra); LOADR(4 * q0 + 0, rb);
    CVTR(4 * q0 - 1, wrap6(m6 + 0), ra); CVTR(4 * q0 + 0, wrap6(m6 + 1), rb);
    LOADR(4 * q0 + 1, ra); LOADR(4 * q0 + 2, rb);
    CVTR(4 * q0 + 1, wrap6(m6 + 2), ra); CVTR(4 * q0 + 2, wrap6(m6 + 3), rb);
    LOADR(4 * q0 + 3, ra); LOADR(4 * q0 + 4, rb);
    CVTR(4 * q0 + 3, wrap6(m6 + 4), ra); CVTR(4 * q0 + 4, wrap6(m6 + 5), rb);
  }
  barrier_lgkm();

  // ---- task loop: prefetch 4 next rows under COMPUTE; barriers are LDS-only ----
#pragma unroll 1
  for (int q = q0; q < qend; ++q) {
    const bool more = (q + 1 < qend);
    // opaque uniform flag: route through VGPR (legal) then readfirstlane to SGPR
    int mflag = more ? 1 : 0;
    asm volatile("" : "+v"(mflag));          // compiler can't see through
    mflag = __builtin_amdgcn_readfirstlane(mflag);
    float ra[NP][4], rb[NP][4], rc[NP][4], rd[NP][4];
    if (mflag) {
      LOADR(4 * q + 5, ra); LOADR(4 * q + 6, rb);
      LOADR(4 * q + 7, rc); LOADR(4 * q + 8, rd);
    }
    COMPUTE(q, m6);                          // hides the prefetch latency
    barrier_lgkm();                          // readers of tile done (lgkm only)
    if (mflag) {
      CVTR(4 * q + 5, m6,            ra);    // counted vmcnt at first use
      CVTR(4 * q + 6, wrap6(m6 + 1), rb);
      CVTR(4 * q + 7, wrap6(m6 + 2), rc);
      CVTR(4 * q + 8, wrap6(m6 + 3), rd);
      barrier_lgkm();                        // tile ready for next task
      m6 = wrap6(m6 + 4);
    }
  }
}

extern "C" __global__ void __launch_bounds__(256, 3) conv_all(
    const float* __restrict__ x, const float* __restrict__ wgt,
    const float* __restrict__ bias, float* __restrict__ out) {
  extern __shared__ ushort_t lds[];
  const int bid = blockIdx.x;
  if (bid < 288)      conv_group<3>(x, wgt, bias, out, lds, bid);        // 288 blocks
  else if (bid < 480) conv_group<2>(x, wgt, bias, out, lds, bid - 288);  // 192
  else if (bid < 672) conv_group<1>(x, wgt, bias, out, lds, bid - 480);  // 192
  else                conv_group<0>(x, wgt, bias, out, lds, bid - 672);  // 192
}

extern "C" void kernel_launch(void* const* d_in, const int* in_sizes, int n_in,
                              void* d_out, int out_size, void* d_ws, size_t ws_size,
                              hipStream_t stream) {
  const float* x    = (const float*)d_in[0];
  const float* wgt  = (const float*)d_in[1];
  const float* bias = (const float*)d_in[2];
  float* out        = (float*)d_out;

  // dynamic LDS (max over groups, G3): 6*196*20*2 + 5120 = 52160 B -> 3 blocks/CU
  const size_t lds_bytes = (size_t)(6 * 196 * CGP + 5 * 4 * 16 * 8) * 2;
  conv_all<<<dim3(864), dim3(256), lds_bytes, stream>>>(x, wgt, bias, out);
}